// Round 2
// baseline (848.618 us; speedup 1.0000x reference)
//
#include <hip/hip_runtime.h>
#include <hip/hip_bf16.h>
#include <math.h>

#define DIM      1024
#define NH       16
#define DH       64
#define NSEQ     1605
#define HWIN     1600
#define PREFIX   5
#define SCALE    0.125f
#define NEG_INF  (-1e30f)

// ===========================================================================
// Shared GEMM helpers: LDS tiles stored [row][k] with 16 data words + 4 pad,
// 16B chunks XOR-swizzled so b128 fragment reads are <=2-way bank aliased.
// ===========================================================================
#define LSTR 20   // words per LDS row (16 + 4 pad)

__device__ __forceinline__ int swz_off(int row, int ch) {
    return row * LSTR + ((ch ^ ((row >> 3) & 3)) << 2);
}

template<int ROWS>
__device__ __forceinline__ void stage_tile(const float* __restrict__ src, int ld,
                                           int row0, int maxrow, int k0,
                                           float* __restrict__ dst, int tid) {
#pragma unroll
    for (int idx = tid; idx < ROWS * 4; idx += 256) {
        int r = idx >> 2, ch = idx & 3;
        int gr = row0 + r;
        float4 v = {0.f, 0.f, 0.f, 0.f};
        if (gr < maxrow) v = *(const float4*)&src[(size_t)gr * ld + k0 + ch * 4];
        *(float4*)&dst[swz_off(r, ch)] = v;
    }
}

__device__ __forceinline__ float dot4(float4 a, float4 b) {
    return a.x * b.x + a.y * b.y + a.z * b.z + a.w * b.w;
}

// ===========================================================================
// GEMM 1: qkv = x @ W_qkv^T -> scatter into head-major Q/K/V [h][seq][64].
// M=1605, N=3072, K=1024. Tile 128x128, BK=16, 256 thr, 8x8 micro (2x4 split).
// ===========================================================================
__global__ __launch_bounds__(256) void gemm_qkv(
    const float* __restrict__ A, const float* __restrict__ B,
    float* __restrict__ Qh, float* __restrict__ Kh, float* __restrict__ Vh,
    int M, int K)
{
    __shared__ float As[128 * LSTR];
    __shared__ float Bs[128 * LSTR];
    const int tid = threadIdx.x;
    const int m0 = blockIdx.y * 128;
    const int n0 = blockIdx.x * 128;
    const int ty = tid >> 4, tx = tid & 15;

    float acc00[4][4] = {}, acc01[4][4] = {}, acc10[4][4] = {}, acc11[4][4] = {};

    for (int k0 = 0; k0 < K; k0 += 16) {
        stage_tile<128>(A, K, m0, M, k0, As, tid);
        stage_tile<128>(B, K, n0, 1 << 30, k0, Bs, tid);
        __syncthreads();
#pragma unroll
        for (int kc = 0; kc < 4; ++kc) {
            float4 a0[4], a1[4], b0[4], b1[4];
#pragma unroll
            for (int i = 0; i < 4; ++i) {
                a0[i] = *(const float4*)&As[swz_off(ty * 4 + i, kc)];
                a1[i] = *(const float4*)&As[swz_off(64 + ty * 4 + i, kc)];
                b0[i] = *(const float4*)&Bs[swz_off(tx * 4 + i, kc)];
                b1[i] = *(const float4*)&Bs[swz_off(64 + tx * 4 + i, kc)];
            }
#pragma unroll
            for (int i = 0; i < 4; ++i)
#pragma unroll
                for (int j = 0; j < 4; ++j) {
                    acc00[i][j] += dot4(a0[i], b0[j]);
                    acc01[i][j] += dot4(a0[i], b1[j]);
                    acc10[i][j] += dot4(a1[i], b0[j]);
                    acc11[i][j] += dot4(a1[i], b1[j]);
                }
        }
        __syncthreads();
    }

    // epilogue: scatter to head-major buffers
    const int which = n0 >> 10;            // 0=Q 1=K 2=V (n0 mult of 128)
    const int hbase = (n0 & 1023) >> 6;    // head for cols 0..63; +1 for 64..127
    float* buf = (which == 0) ? Qh : (which == 1) ? Kh : Vh;
#pragma unroll
    for (int rh = 0; rh < 2; ++rh) {
#pragma unroll
        for (int i = 0; i < 4; ++i) {
            int gm = m0 + rh * 64 + ty * 4 + i;
            if (gm < M) {
                float4 v0, v1;
                if (rh == 0) {
                    v0 = make_float4(acc00[i][0], acc00[i][1], acc00[i][2], acc00[i][3]);
                    v1 = make_float4(acc01[i][0], acc01[i][1], acc01[i][2], acc01[i][3]);
                } else {
                    v0 = make_float4(acc10[i][0], acc10[i][1], acc10[i][2], acc10[i][3]);
                    v1 = make_float4(acc11[i][0], acc11[i][1], acc11[i][2], acc11[i][3]);
                }
                *(float4*)&buf[((size_t)hbase * NSEQ + gm) * DH + tx * 4] = v0;
                *(float4*)&buf[((size_t)(hbase + 1) * NSEQ + gm) * DH + tx * 4] = v1;
            }
        }
    }
}

// ===========================================================================
// RoPE in place on Q and K. One block = (seq row, Q-or-K); wave = one head.
// ===========================================================================
__global__ __launch_bounds__(256) void rope_kernel(
    float* __restrict__ Qh, float* __restrict__ Kh, const float* __restrict__ rope)
{
    const int r = blockIdx.x;               // 0..HWIN-1
    float* base = (blockIdx.y == 0) ? Qh : Kh;
    const int lane = threadIdx.x & 63;      // dim 0..63
    const int w = threadIdx.x >> 6;         // wave 0..3
    const float s = rope[(size_t)r * DH + lane];
    const float c = rope[(size_t)HWIN * DH + (size_t)r * DH + lane];
#pragma unroll
    for (int g = 0; g < 4; ++g) {
        int h = w + g * 4;
        float* t = base + ((size_t)h * NSEQ + PREFIX + r) * DH + lane;
        float v = *t;
        float partner = __shfl_xor(v, 32);
        float rot = (lane < 32) ? -partner : partner;
        *t = v * c + rot * s;
    }
}

// ===========================================================================
// Streaming attention: one block = (head, 64-query tile); 256 threads.
// Score tile S[64][64]: thread (rq=tid>>4, rk=tid&15) owns rows {rq*4+i},
// cols {rk+16j} (interleaved -> 2-way LDS aliasing = free). m/l in registers
// (redundant across the 16-thread row group via shfl reductions).
// PV: thread owns O rows {rq*4+i}, dims {rk*4+j}; P read b128 (broadcast).
// ===========================================================================
#define ASTR 68   // attn LDS row stride (words)

__global__ __launch_bounds__(256) void attn_kernel(
    const float* __restrict__ Qh, const float* __restrict__ Kh,
    const float* __restrict__ Vh, float* __restrict__ O)
{
    __shared__ float qs[64 * ASTR];
    __shared__ float ks[64 * ASTR];
    __shared__ float vs[64 * ASTR];
    __shared__ float ps[64 * ASTR];

    const int h  = blockIdx.y;
    const int q0 = blockIdx.x * 64;
    const int tid = threadIdx.x;
    const int rq = tid >> 4;      // q-row group 0..15 (rows rq*4..+3)
    const int rk = tid & 15;      // k-col lane (cols rk+16j)

    // stage Q tile (pre-scaled)
    for (int idx = tid; idx < 64 * 16; idx += 256) {
        int rr = idx >> 4, c4 = (idx & 15) * 4;
        int q = q0 + rr;
        float4 v = {0.f, 0.f, 0.f, 0.f};
        if (q < NSEQ) v = *(const float4*)&Qh[((size_t)h * NSEQ + q) * DH + c4];
        v.x *= SCALE; v.y *= SCALE; v.z *= SCALE; v.w *= SCALE;
        *(float4*)&qs[rr * ASTR + c4] = v;
    }

    float m[4], l[4], o[4][4] = {};
#pragma unroll
    for (int i = 0; i < 4; ++i) { m[i] = NEG_INF; l[i] = 0.f; }

    for (int j0 = 0; j0 < NSEQ; j0 += 64) {
        __syncthreads();   // ks/vs/ps free (also covers q-stage on first iter)
        for (int idx = tid; idx < 64 * 16; idx += 256) {
            int rr = idx >> 4, c4 = (idx & 15) * 4;
            int j = j0 + rr;
            float4 kv = {0.f, 0.f, 0.f, 0.f}, vv = {0.f, 0.f, 0.f, 0.f};
            if (j < NSEQ) {
                kv = *(const float4*)&Kh[((size_t)h * NSEQ + j) * DH + c4];
                vv = *(const float4*)&Vh[((size_t)h * NSEQ + j) * DH + c4];
            }
            *(float4*)&ks[rr * ASTR + c4] = kv;
            *(float4*)&vs[rr * ASTR + c4] = vv;
        }
        __syncthreads();

        // ---- scores: 4q x 4k per thread ----
        float s[4][4] = {};
#pragma unroll 4
        for (int d4 = 0; d4 < DH; d4 += 4) {
            float4 a[4], b[4];
#pragma unroll
            for (int i = 0; i < 4; ++i) a[i] = *(const float4*)&qs[(rq * 4 + i) * ASTR + d4];
#pragma unroll
            for (int j = 0; j < 4; ++j) b[j] = *(const float4*)&ks[(rk + 16 * j) * ASTR + d4];
#pragma unroll
            for (int i = 0; i < 4; ++i)
#pragma unroll
                for (int j = 0; j < 4; ++j) s[i][j] += dot4(a[i], b[j]);
        }
#pragma unroll
        for (int j = 0; j < 4; ++j)
            if (j0 + rk + 16 * j >= NSEQ) {
#pragma unroll
                for (int i = 0; i < 4; ++i) s[i][j] = NEG_INF;
            }

        // ---- online softmax (register m/l, shfl over 16-lane row group) ----
#pragma unroll
        for (int i = 0; i < 4; ++i) {
            float mt = fmaxf(fmaxf(s[i][0], s[i][1]), fmaxf(s[i][2], s[i][3]));
#pragma unroll
            for (int off = 1; off < 16; off <<= 1)
                mt = fmaxf(mt, __shfl_xor(mt, off));
            float mn = fmaxf(m[i], mt);
            float so = __expf(m[i] - mn);
            float pl = 0.f;
#pragma unroll
            for (int j = 0; j < 4; ++j) {
                float p = __expf(s[i][j] - mn);
                ps[(rq * 4 + i) * ASTR + rk + 16 * j] = p;
                pl += p;
            }
#pragma unroll
            for (int off = 1; off < 16; off <<= 1)
                pl += __shfl_xor(pl, off);
            l[i] = l[i] * so + pl;
            m[i] = mn;
#pragma unroll
            for (int j = 0; j < 4; ++j) o[i][j] *= so;
        }
        __syncthreads();   // ps visible

        // ---- PV: 4-key chunks, b128 P (broadcast) + b128 V ----
#pragma unroll 4
        for (int kk = 0; kk < 64; kk += 4) {
            float4 pr[4], vv[4];
#pragma unroll
            for (int i = 0; i < 4; ++i) pr[i] = *(const float4*)&ps[(rq * 4 + i) * ASTR + kk];
#pragma unroll
            for (int t = 0; t < 4; ++t) vv[t] = *(const float4*)&vs[(kk + t) * ASTR + rk * 4];
#pragma unroll
            for (int i = 0; i < 4; ++i) {
                o[i][0] += pr[i].x * vv[0].x + pr[i].y * vv[1].x + pr[i].z * vv[2].x + pr[i].w * vv[3].x;
                o[i][1] += pr[i].x * vv[0].y + pr[i].y * vv[1].y + pr[i].z * vv[2].y + pr[i].w * vv[3].y;
                o[i][2] += pr[i].x * vv[0].z + pr[i].y * vv[1].z + pr[i].z * vv[2].z + pr[i].w * vv[3].z;
                o[i][3] += pr[i].x * vv[0].w + pr[i].y * vv[1].w + pr[i].z * vv[2].w + pr[i].w * vv[3].w;
            }
        }
    }

    // epilogue
#pragma unroll
    for (int i = 0; i < 4; ++i) {
        int q = q0 + rq * 4 + i;
        if (q < NSEQ) {
            float inv = 1.0f / l[i];
            float4 v = {o[i][0] * inv, o[i][1] * inv, o[i][2] * inv, o[i][3] * inv};
            *(float4*)&O[(size_t)q * DIM + h * DH + rk * 4] = v;
        }
    }
}

// ===========================================================================
// GEMM 2: out = O @ W_proj^T + b. M=1605, N=1024, K=1024.
// Tile 64x128, BK=16, 256 thr, 8x4 micro (cols interleaved by 32).
// ===========================================================================
__global__ __launch_bounds__(256) void gemm_proj(
    const float* __restrict__ A, const float* __restrict__ B,
    const float* __restrict__ bias, float* __restrict__ C,
    int M, int K)
{
    __shared__ float As[64 * LSTR];
    __shared__ float Bs[128 * LSTR];
    const int tid = threadIdx.x;
    const int m0 = blockIdx.y * 64;
    const int n0 = blockIdx.x * 128;
    const int ty = tid >> 5, tx = tid & 31;

    float acc[8][4] = {};

    for (int k0 = 0; k0 < K; k0 += 16) {
        stage_tile<64>(A, K, m0, M, k0, As, tid);
        stage_tile<128>(B, K, n0, 1 << 30, k0, Bs, tid);
        __syncthreads();
#pragma unroll
        for (int kc = 0; kc < 4; ++kc) {
            float4 a[8], b[4];
#pragma unroll
            for (int i = 0; i < 8; ++i) a[i] = *(const float4*)&As[swz_off(ty * 8 + i, kc)];
#pragma unroll
            for (int j = 0; j < 4; ++j) b[j] = *(const float4*)&Bs[swz_off(tx + 32 * j, kc)];
#pragma unroll
            for (int i = 0; i < 8; ++i)
#pragma unroll
                for (int j = 0; j < 4; ++j) acc[i][j] += dot4(a[i], b[j]);
        }
        __syncthreads();
    }

    float bv[4];
#pragma unroll
    for (int j = 0; j < 4; ++j) bv[j] = bias[n0 + tx + 32 * j];
#pragma unroll
    for (int i = 0; i < 8; ++i) {
        int gm = m0 + ty * 8 + i;
        if (gm < M) {
#pragma unroll
            for (int j = 0; j < 4; ++j)
                C[(size_t)gm * DIM + n0 + tx + 32 * j] = acc[i][j] + bv[j];
        }
    }
}

// ===========================================================================
extern "C" void kernel_launch(void* const* d_in, const int* in_sizes, int n_in,
                              void* d_out, int out_size, void* d_ws, size_t ws_size,
                              hipStream_t stream)
{
    const float* x     = (const float*)d_in[0];
    const float* rope  = (const float*)d_in[1];
    const float* Wqkv  = (const float*)d_in[2];
    const float* Wproj = (const float*)d_in[3];
    const float* bproj = (const float*)d_in[4];
    float* out = (float*)d_out;

    float* ws = (float*)d_ws;
    const size_t HS = (size_t)NH * NSEQ * DH;
    float* Qh = ws;
    float* Kh = ws + HS;
    float* Vh = ws + 2 * HS;
    float* O  = ws + 3 * HS;

    gemm_qkv<<<dim3(3 * DIM / 128, (NSEQ + 127) / 128), 256, 0, stream>>>(
        x, Wqkv, Qh, Kh, Vh, NSEQ, DIM);

    rope_kernel<<<dim3(HWIN, 2), 256, 0, stream>>>(Qh, Kh, rope);

    attn_kernel<<<dim3((NSEQ + 63) / 64, NH), 256, 0, stream>>>(Qh, Kh, Vh, O);

    gemm_proj<<<dim3(DIM / 128, (NSEQ + 63) / 64), 256, 0, stream>>>(
        O, Wproj, bproj, out, NSEQ, DIM);
}

// Round 4
// 316.080 us; speedup vs baseline: 2.6848x; 2.6848x over previous
//
#include <hip/hip_runtime.h>
#include <hip/hip_bf16.h>
#include <math.h>

#define DIM    1024
#define NH     16
#define DH     64
#define NSEQ   1605
#define HWIN   1600
#define PREFIX 5

typedef __bf16 bf16_t;
typedef bf16_t bf16x8 __attribute__((ext_vector_type(8)));
typedef bf16_t bf16x4 __attribute__((ext_vector_type(4)));
typedef float  f32x4  __attribute__((ext_vector_type(4)));

#define MFMA(a, b, c) __builtin_amdgcn_mfma_f32_16x16x32_bf16(a, b, c, 0, 0, 0)

struct Split4 { bf16x4 h, l; };

// split fp32x4 -> hi + lo bf16x4 (for 3-product compensated MFMA)
__device__ __forceinline__ Split4 split4(float4 v) {
    Split4 r;
    float h0 = (float)(bf16_t)v.x, h1 = (float)(bf16_t)v.y;
    float h2 = (float)(bf16_t)v.z, h3 = (float)(bf16_t)v.w;
    r.h[0] = (bf16_t)v.x; r.h[1] = (bf16_t)v.y;
    r.h[2] = (bf16_t)v.z; r.h[3] = (bf16_t)v.w;
    r.l[0] = (bf16_t)(v.x - h0); r.l[1] = (bf16_t)(v.y - h1);
    r.l[2] = (bf16_t)(v.z - h2); r.l[3] = (bf16_t)(v.w - h3);
    return r;
}

#define GSTR 40   // GEMM LDS k-stride in halves (80B: 16B-aligned, 2-way bank alias)

// ===========================================================================
// GEMM 1: qkv = x @ W_qkv^T (split-bf16 MFMA). Tile 128x128, BK=32, 4 waves,
// wave = 64x64 = 4x4 MFMA tiles. Epilogue: fold 1/8 into Q, apply RoPE in
// registers (partner d^32 == acc[rt][ct^2], same lane), split Q/K -> hi/lo
// bf16 head-major; V -> fp32 head-major.
// ===========================================================================
__global__ __launch_bounds__(256) void gemm_qkv(
    const float* __restrict__ A, const float* __restrict__ B,
    const float* __restrict__ rope,
    bf16_t* __restrict__ Qhi, bf16_t* __restrict__ Qlo,
    bf16_t* __restrict__ Khi, bf16_t* __restrict__ Klo,
    float* __restrict__ Vf)
{
    __shared__ bf16_t Ah[128 * GSTR], Al[128 * GSTR];
    __shared__ bf16_t Bh[128 * GSTR], Bl[128 * GSTR];

    const int tid = threadIdx.x;
    const int m0 = blockIdx.y * 128, n0 = blockIdx.x * 128;
    const int w = tid >> 6, l = tid & 63;
    const int wr = (w >> 1) * 64, wc = (w & 1) * 64;
    const int lr = l & 15, lg = l >> 4;

    f32x4 acc[4][4] = {};

    for (int k0 = 0; k0 < DIM; k0 += 32) {
#pragma unroll
        for (int t = 0; t < 4; ++t) {
            int idx = tid + 256 * t;
            int r = idx >> 3, c = idx & 7;
            // A tile (guard rows)
            int gr = m0 + r;
            float4 v = make_float4(0.f, 0.f, 0.f, 0.f);
            if (gr < NSEQ) v = *(const float4*)&A[(size_t)gr * DIM + k0 + c * 4];
            Split4 sa = split4(v);
            *(bf16x4*)&Ah[r * GSTR + c * 4] = sa.h;
            *(bf16x4*)&Al[r * GSTR + c * 4] = sa.l;
            // B tile (N=3072, no guard)
            float4 u = *(const float4*)&B[(size_t)(n0 + r) * DIM + k0 + c * 4];
            Split4 sb = split4(u);
            *(bf16x4*)&Bh[r * GSTR + c * 4] = sb.h;
            *(bf16x4*)&Bl[r * GSTR + c * 4] = sb.l;
        }
        __syncthreads();

        bf16x8 ah[4], al[4];
#pragma unroll
        for (int rt = 0; rt < 4; ++rt) {
            ah[rt] = *(const bf16x8*)&Ah[(wr + 16 * rt + lr) * GSTR + lg * 8];
            al[rt] = *(const bf16x8*)&Al[(wr + 16 * rt + lr) * GSTR + lg * 8];
        }
#pragma unroll
        for (int ct = 0; ct < 4; ++ct) {
            bf16x8 bh = *(const bf16x8*)&Bh[(wc + 16 * ct + lr) * GSTR + lg * 8];
            bf16x8 bl = *(const bf16x8*)&Bl[(wc + 16 * ct + lr) * GSTR + lg * 8];
#pragma unroll
            for (int rt = 0; rt < 4; ++rt) {
                acc[rt][ct] = MFMA(al[rt], bh, acc[rt][ct]);
                acc[rt][ct] = MFMA(ah[rt], bl, acc[rt][ct]);
                acc[rt][ct] = MFMA(ah[rt], bh, acc[rt][ct]);
            }
        }
        __syncthreads();
    }

    // ---- epilogue ----
    const int which = n0 >> 10;                 // 0=Q 1=K 2=V (tiles never straddle)
    const int hbase = ((n0 & 1023) + wc) >> 6;  // head (uniform per wave)
    const float qscale = (which == 0) ? 0.125f : 1.0f;

#pragma unroll
    for (int ct = 0; ct < 4; ++ct) {
        int d = 16 * ct + lr;
#pragma unroll
        for (int rt = 0; rt < 4; ++rt) {
#pragma unroll
            for (int reg = 0; reg < 4; ++reg) {
                int seq = m0 + wr + 16 * rt + 4 * lg + reg;
                if (seq >= NSEQ) continue;
                size_t off = ((size_t)hbase * NSEQ + seq) * DH + d;
                float val = acc[rt][ct][reg];
                if (which == 2) {
                    Vf[off] = val;
                } else {
                    val *= qscale;
                    float o = val;
                    if (seq >= PREFIX) {
                        float partner = acc[rt][ct ^ 2][reg] * qscale;
                        float rot = (d < 32) ? -partner : partner;
                        float sn = rope[(size_t)(seq - PREFIX) * DH + d];
                        float cs = rope[(size_t)HWIN * DH + (size_t)(seq - PREFIX) * DH + d];
                        o = val * cs + rot * sn;
                    }
                    bf16_t hh = (bf16_t)o;
                    bf16_t ll = (bf16_t)(o - (float)hh);
                    if (which == 0) { Qhi[off] = hh; Qlo[off] = ll; }
                    else           { Khi[off] = hh; Klo[off] = ll; }
                }
            }
        }
    }
}

// ===========================================================================
// Flash attention: block = (head, 64-q tile), 4 waves, wave = 16 q rows.
// Q frags in registers for the whole sweep. K hi/lo + V^T + P in LDS.
// 16x16x32 MFMA; split-3 for QK^T; online softmax on C-layout rows.
// ===========================================================================
#define ASTRH 72   // LDS row stride in halves (144B: 16B-aligned, 2-way alias)

__global__ __launch_bounds__(256) void attn_kernel(
    const bf16_t* __restrict__ Qhi, const bf16_t* __restrict__ Qlo,
    const bf16_t* __restrict__ Khi, const bf16_t* __restrict__ Klo,
    const float* __restrict__ Vf, float* __restrict__ O)
{
    __shared__ bf16_t Ks[64 * ASTRH], Kl[64 * ASTRH];
    __shared__ bf16_t VT[64 * ASTRH], PS[64 * ASTRH];

    const int h = blockIdx.y;
    const int q0 = blockIdx.x * 64;
    const int tid = threadIdx.x;
    const int w = tid >> 6, l = tid & 63;
    const int lr = l & 15, lg = l >> 4;

    // Q fragments (held in registers the whole kernel); rows q0+16w+lr
    bf16x8 qh[2], ql[2];
    {
        int qrow = q0 + 16 * w + lr;
#pragma unroll
        for (int ks = 0; ks < 2; ++ks) {
            if (qrow < NSEQ) {
                size_t off = ((size_t)h * NSEQ + qrow) * DH + 32 * ks + lg * 8;
                qh[ks] = *(const bf16x8*)&Qhi[off];
                ql[ks] = *(const bf16x8*)&Qlo[off];
            } else {
                qh[ks] = (bf16x8)(bf16_t)0.0f;
                ql[ks] = (bf16x8)(bf16_t)0.0f;
            }
        }
    }

    f32x4 o[4] = {};
    float m[4], lsum[4];
#pragma unroll
    for (int r = 0; r < 4; ++r) { m[r] = -1e30f; lsum[r] = 0.f; }

    for (int j0 = 0; j0 < NSEQ; j0 += 64) {
        __syncthreads();   // previous tile fully consumed
        // stage K hi/lo (bf16 rows, straight copy)
#pragma unroll
        for (int t = 0; t < 2; ++t) {
            int idx = tid + 256 * t;
            int row = idx >> 3, ch = idx & 7;
            int j = j0 + row;
            uint4 kv = make_uint4(0, 0, 0, 0), lv = make_uint4(0, 0, 0, 0);
            if (j < NSEQ) {
                size_t off = ((size_t)h * NSEQ + j) * DH + ch * 8;
                kv = *(const uint4*)&Khi[off];
                lv = *(const uint4*)&Klo[off];
            }
            *(uint4*)&Ks[row * ASTRH + ch * 8] = kv;
            *(uint4*)&Kl[row * ASTRH + ch * 8] = lv;
        }
        // stage V transposed (fp32 -> bf16)
#pragma unroll
        for (int t = 0; t < 4; ++t) {
            int idx = tid + 256 * t;
            int row = idx >> 4, c4 = idx & 15;
            int j = j0 + row;
            float4 v = make_float4(0.f, 0.f, 0.f, 0.f);
            if (j < NSEQ) v = *(const float4*)&Vf[((size_t)h * NSEQ + j) * DH + c4 * 4];
            VT[(c4 * 4 + 0) * ASTRH + row] = (bf16_t)v.x;
            VT[(c4 * 4 + 1) * ASTRH + row] = (bf16_t)v.y;
            VT[(c4 * 4 + 2) * ASTRH + row] = (bf16_t)v.z;
            VT[(c4 * 4 + 3) * ASTRH + row] = (bf16_t)v.w;
        }
        __syncthreads();

        // ---- QK^T (split-3) ----
        f32x4 s[4] = {};
#pragma unroll
        for (int ct = 0; ct < 4; ++ct) {
#pragma unroll
            for (int ks = 0; ks < 2; ++ks) {
                bf16x8 bh = *(const bf16x8*)&Ks[(16 * ct + lr) * ASTRH + 32 * ks + lg * 8];
                bf16x8 bl = *(const bf16x8*)&Kl[(16 * ct + lr) * ASTRH + 32 * ks + lg * 8];
                s[ct] = MFMA(ql[ks], bh, s[ct]);
                s[ct] = MFMA(qh[ks], bl, s[ct]);
                s[ct] = MFMA(qh[ks], bh, s[ct]);
            }
            if (j0 + 16 * ct + lr >= NSEQ) {
                s[ct][0] = -1e30f; s[ct][1] = -1e30f;
                s[ct][2] = -1e30f; s[ct][3] = -1e30f;
            }
        }

        // ---- online softmax (rows = 4*lg + reg, reduce over 16-lane group) ----
        float so[4];
#pragma unroll
        for (int reg = 0; reg < 4; ++reg) {
            float mt = fmaxf(fmaxf(s[0][reg], s[1][reg]), fmaxf(s[2][reg], s[3][reg]));
#pragma unroll
            for (int off = 1; off < 16; off <<= 1)
                mt = fmaxf(mt, __shfl_xor(mt, off));
            float mn = fmaxf(m[reg], mt);
            so[reg] = __expf(m[reg] - mn);
            m[reg] = mn;
            float psum = 0.f;
#pragma unroll
            for (int ct = 0; ct < 4; ++ct) {
                float p = __expf(s[ct][reg] - mn);
                s[ct][reg] = p;
                psum += p;
            }
#pragma unroll
            for (int off = 1; off < 16; off <<= 1)
                psum += __shfl_xor(psum, off);
            lsum[reg] = lsum[reg] * so[reg] + psum;
        }

        // write P (bf16), wave-private rows
#pragma unroll
        for (int ct = 0; ct < 4; ++ct)
#pragma unroll
            for (int reg = 0; reg < 4; ++reg)
                PS[(16 * w + 4 * lg + reg) * ASTRH + 16 * ct + lr] = (bf16_t)s[ct][reg];

        // rescale O accumulators
#pragma unroll
        for (int ct = 0; ct < 4; ++ct)
#pragma unroll
            for (int reg = 0; reg < 4; ++reg)
                o[ct][reg] *= so[reg];

        // ---- PV ----
#pragma unroll
        for (int ks = 0; ks < 2; ++ks) {
            bf16x8 pa = *(const bf16x8*)&PS[(16 * w + lr) * ASTRH + 32 * ks + lg * 8];
#pragma unroll
            for (int ct = 0; ct < 4; ++ct) {
                bf16x8 vb = *(const bf16x8*)&VT[(16 * ct + lr) * ASTRH + 32 * ks + lg * 8];
                o[ct] = MFMA(pa, vb, o[ct]);
            }
        }
    }

    // ---- store O[seq][h*64+d] ----
#pragma unroll
    for (int ct = 0; ct < 4; ++ct) {
#pragma unroll
        for (int reg = 0; reg < 4; ++reg) {
            int seq = q0 + 16 * w + 4 * lg + reg;
            if (seq < NSEQ)
                O[(size_t)seq * DIM + h * DH + 16 * ct + lr] = o[ct][reg] / lsum[reg];
        }
    }
}

// ===========================================================================
// GEMM 2: out = O @ W_proj^T + b (split-bf16 MFMA). Tile 64x64, BK=32,
// 4 waves (2x2), wave = 32x32 = 2x2 MFMA tiles.
// ===========================================================================
__global__ __launch_bounds__(256) void gemm_proj(
    const float* __restrict__ A, const float* __restrict__ B,
    const float* __restrict__ bias, float* __restrict__ C)
{
    __shared__ bf16_t Ah[64 * GSTR], Al[64 * GSTR];
    __shared__ bf16_t Bh[64 * GSTR], Bl[64 * GSTR];

    const int tid = threadIdx.x;
    const int m0 = blockIdx.y * 64, n0 = blockIdx.x * 64;
    const int w = tid >> 6, l = tid & 63;
    const int wr = (w >> 1) * 32, wc = (w & 1) * 32;
    const int lr = l & 15, lg = l >> 4;

    f32x4 acc[2][2] = {};

    for (int k0 = 0; k0 < DIM; k0 += 32) {
#pragma unroll
        for (int t = 0; t < 2; ++t) {
            int idx = tid + 256 * t;
            int r = idx >> 3, c = idx & 7;
            int gr = m0 + r;
            float4 v = make_float4(0.f, 0.f, 0.f, 0.f);
            if (gr < NSEQ) v = *(const float4*)&A[(size_t)gr * DIM + k0 + c * 4];
            Split4 sa = split4(v);
            *(bf16x4*)&Ah[r * GSTR + c * 4] = sa.h;
            *(bf16x4*)&Al[r * GSTR + c * 4] = sa.l;
            float4 u = *(const float4*)&B[(size_t)(n0 + r) * DIM + k0 + c * 4];
            Split4 sb = split4(u);
            *(bf16x4*)&Bh[r * GSTR + c * 4] = sb.h;
            *(bf16x4*)&Bl[r * GSTR + c * 4] = sb.l;
        }
        __syncthreads();

        bf16x8 ah[2], al[2];
#pragma unroll
        for (int rt = 0; rt < 2; ++rt) {
            ah[rt] = *(const bf16x8*)&Ah[(wr + 16 * rt + lr) * GSTR + lg * 8];
            al[rt] = *(const bf16x8*)&Al[(wr + 16 * rt + lr) * GSTR + lg * 8];
        }
#pragma unroll
        for (int ct = 0; ct < 2; ++ct) {
            bf16x8 bh = *(const bf16x8*)&Bh[(wc + 16 * ct + lr) * GSTR + lg * 8];
            bf16x8 bl = *(const bf16x8*)&Bl[(wc + 16 * ct + lr) * GSTR + lg * 8];
#pragma unroll
            for (int rt = 0; rt < 2; ++rt) {
                acc[rt][ct] = MFMA(al[rt], bh, acc[rt][ct]);
                acc[rt][ct] = MFMA(ah[rt], bl, acc[rt][ct]);
                acc[rt][ct] = MFMA(ah[rt], bh, acc[rt][ct]);
            }
        }
        __syncthreads();
    }

#pragma unroll
    for (int ct = 0; ct < 2; ++ct) {
        int n = n0 + wc + 16 * ct + lr;
        float bv = bias[n];
#pragma unroll
        for (int rt = 0; rt < 2; ++rt) {
#pragma unroll
            for (int reg = 0; reg < 4; ++reg) {
                int seq = m0 + wr + 16 * rt + 4 * lg + reg;
                if (seq < NSEQ)
                    C[(size_t)seq * DIM + n] = acc[rt][ct][reg] + bv;
            }
        }
    }
}

// ===========================================================================
extern "C" void kernel_launch(void* const* d_in, const int* in_sizes, int n_in,
                              void* d_out, int out_size, void* d_ws, size_t ws_size,
                              hipStream_t stream)
{
    const float* x     = (const float*)d_in[0];
    const float* rope  = (const float*)d_in[1];
    const float* Wqkv  = (const float*)d_in[2];
    const float* Wproj = (const float*)d_in[3];
    const float* bproj = (const float*)d_in[4];
    float* out = (float*)d_out;

    float* ws = (float*)d_ws;
    const size_t HS = (size_t)NH * NSEQ * DH;   // 1,643,520
    float* Vf = ws;
    float* O  = ws + HS;
    bf16_t* Qhi = (bf16_t*)(ws + 2 * HS);
    bf16_t* Qlo = Qhi + HS;
    bf16_t* Khi = Qlo + HS;
    bf16_t* Klo = Khi + HS;

    gemm_qkv<<<dim3(3 * DIM / 128, (NSEQ + 127) / 128), 256, 0, stream>>>(
        x, Wqkv, rope, Qhi, Qlo, Khi, Klo, Vf);

    attn_kernel<<<dim3((NSEQ + 63) / 64, NH), 256, 0, stream>>>(
        Qhi, Qlo, Khi, Klo, Vf, O);

    gemm_proj<<<dim3(DIM / 64, (NSEQ + 63) / 64), 256, 0, stream>>>(
        O, Wproj, bproj, out);
}